// Round 1
// baseline (276.475 us; speedup 1.0000x reference)
//
#include <hip/hip_runtime.h>

#define NNODES 10000
#define F 256
#define H 512
#define CH 256

typedef _Float16 half8 __attribute__((ext_vector_type(8)));
typedef float floatx4 __attribute__((ext_vector_type(4)));

// ---------- CSR build ----------
__global__ __launch_bounds__(256) void count_k(const int* __restrict__ dst,
                                               int* __restrict__ cnt, int E) {
  int e = blockIdx.x * blockDim.x + threadIdx.x;
  if (e < E) atomicAdd(&cnt[dst[e]], 1);
}

__global__ __launch_bounds__(1024) void scan_k(const int* __restrict__ cnt,
                                               int* __restrict__ offs,
                                               float* __restrict__ dinv, int N) {
  __shared__ int s[1024];
  __shared__ int carry_s;
  int tid = threadIdx.x;
  if (tid == 0) carry_s = 0;
  __syncthreads();
  for (int base = 0; base < N; base += 1024) {
    int i = base + tid;
    int v = (i < N) ? cnt[i] : 0;
    s[tid] = v;
    __syncthreads();
    for (int o = 1; o < 1024; o <<= 1) {
      int t = (tid >= o) ? s[tid - o] : 0;
      __syncthreads();
      s[tid] += t;
      __syncthreads();
    }
    int incl = s[tid];
    int carry = carry_s;
    if (i < N) {
      offs[i] = carry + incl - v;           // exclusive prefix
      dinv[i] = rsqrtf((float)(v + 1));     // deg includes self-loop
    }
    __syncthreads();
    if (tid == 1023) carry_s = carry + s[1023];
    __syncthreads();
  }
  if (tid == 0) offs[N] = carry_s;
}

__global__ __launch_bounds__(256) void fill_k(const int* __restrict__ src,
                                              const int* __restrict__ dst,
                                              const int* __restrict__ offs,
                                              int* __restrict__ cursor,
                                              int* __restrict__ csr, int E) {
  int e = blockIdx.x * blockDim.x + threadIdx.x;
  if (e < E) {
    int d = dst[e];
    int p = atomicAdd(&cursor[d], 1);
    csr[offs[d] + p] = src[e];
  }
}

// ---------- weight transpose + f16 convert: W (K x Nc) -> Wt (Nc x K) ----------
__global__ __launch_bounds__(256) void convw_k(const float* __restrict__ W,
                                               _Float16* __restrict__ Wt,
                                               int K, int Nc) {
  int t = blockIdx.x * blockDim.x + threadIdx.x;
  if (t < Nc * K) {
    int n = t / K, k = t - n * K;
    Wt[t] = (_Float16)W[k * Nc + n];
  }
}

// ---------- layer-1 aggregation over raw x (256 feats), writes f16 ----------
__global__ __launch_bounds__(256) void agg1_k(const float* __restrict__ x,
                                              const int* __restrict__ offs,
                                              const int* __restrict__ csr,
                                              const float* __restrict__ dinv,
                                              _Float16* __restrict__ axh, int N) {
  __shared__ int s_src[CH];
  __shared__ float s_w[CH];
  int f = threadIdx.x;  // 256 threads = 256 features
  for (int node = blockIdx.x; node < N; node += gridDim.x) {
    int beg = offs[node], end = offs[node + 1];
    float di = dinv[node];
    float acc = 0.f;
    for (int c = beg; c < end; c += CH) {
      int m = min(CH, end - c);
      __syncthreads();
      if (f < m) { int s = csr[c + f]; s_src[f] = s; s_w[f] = dinv[s]; }
      __syncthreads();
      #pragma unroll 4
      for (int e = 0; e < m; e++) acc += s_w[e] * x[s_src[e] * F + f];
    }
    float total = di * acc + di * di * x[node * F + f];
    axh[node * F + f] = (_Float16)total;
  }
}

// ---------- GEMM1: (N x 256 f16) @ W1t (512 x 256 f16, n-major) -> relu(+b1) f16 ----------
__global__ __launch_bounds__(256) void gemm1_k(const _Float16* __restrict__ A,
                                               const _Float16* __restrict__ Bt,
                                               const float* __restrict__ bias,
                                               _Float16* __restrict__ Cc) {
  int lane = threadIdx.x & 63;
  int wv = threadIdx.x >> 6;
  int m0 = blockIdx.x * 16;
  int nb = blockIdx.y * 256 + wv * 64;
  int r = lane & 15, q = lane >> 4;
  floatx4 a0 = {0,0,0,0}, a1 = {0,0,0,0}, a2 = {0,0,0,0}, a3 = {0,0,0,0};
  const _Float16* Ap = A + (size_t)(m0 + r) * F + q * 8;
  const _Float16* Bp = Bt + (size_t)(nb + r) * F + q * 8;
  for (int k0 = 0; k0 < F; k0 += 32) {
    half8 a  = *(const half8*)(Ap + k0);
    half8 b0 = *(const half8*)(Bp + k0);
    half8 b1v = *(const half8*)(Bp + 16 * F + k0);
    half8 b2v = *(const half8*)(Bp + 32 * F + k0);
    half8 b3v = *(const half8*)(Bp + 48 * F + k0);
    a0 = __builtin_amdgcn_mfma_f32_16x16x32_f16(a, b0, a0, 0, 0, 0);
    a1 = __builtin_amdgcn_mfma_f32_16x16x32_f16(a, b1v, a1, 0, 0, 0);
    a2 = __builtin_amdgcn_mfma_f32_16x16x32_f16(a, b2v, a2, 0, 0, 0);
    a3 = __builtin_amdgcn_mfma_f32_16x16x32_f16(a, b3v, a3, 0, 0, 0);
  }
  floatx4 accs[4] = {a0, a1, a2, a3};
  #pragma unroll
  for (int nn = 0; nn < 4; nn++) {
    #pragma unroll
    for (int rr = 0; rr < 4; rr++) {
      int row = q * 4 + rr;
      int n = nb + nn * 16 + r;
      float v = accs[nn][rr] + bias[n];
      v = fmaxf(v, 0.f);
      Cc[(size_t)(m0 + row) * H + n] = (_Float16)v;
    }
  }
}

// ---------- GEMM2: (N x 512 f16) @ W2t (256 x 512 f16) -> xw2 f16 (no bias) ----------
__global__ __launch_bounds__(256) void gemm2_k(const _Float16* __restrict__ A,
                                               const _Float16* __restrict__ Bt,
                                               _Float16* __restrict__ Cc) {
  int lane = threadIdx.x & 63;
  int wv = threadIdx.x >> 6;
  int m0 = blockIdx.x * 16;
  int nb = wv * 64;
  int r = lane & 15, q = lane >> 4;
  floatx4 a0 = {0,0,0,0}, a1 = {0,0,0,0}, a2 = {0,0,0,0}, a3 = {0,0,0,0};
  const _Float16* Ap = A + (size_t)(m0 + r) * H + q * 8;
  const _Float16* Bp = Bt + (size_t)(nb + r) * H + q * 8;
  for (int k0 = 0; k0 < H; k0 += 32) {
    half8 a  = *(const half8*)(Ap + k0);
    half8 b0 = *(const half8*)(Bp + k0);
    half8 b1v = *(const half8*)(Bp + 16 * H + k0);
    half8 b2v = *(const half8*)(Bp + 32 * H + k0);
    half8 b3v = *(const half8*)(Bp + 48 * H + k0);
    a0 = __builtin_amdgcn_mfma_f32_16x16x32_f16(a, b0, a0, 0, 0, 0);
    a1 = __builtin_amdgcn_mfma_f32_16x16x32_f16(a, b1v, a1, 0, 0, 0);
    a2 = __builtin_amdgcn_mfma_f32_16x16x32_f16(a, b2v, a2, 0, 0, 0);
    a3 = __builtin_amdgcn_mfma_f32_16x16x32_f16(a, b3v, a3, 0, 0, 0);
  }
  floatx4 accs[4] = {a0, a1, a2, a3};
  #pragma unroll
  for (int nn = 0; nn < 4; nn++) {
    #pragma unroll
    for (int rr = 0; rr < 4; rr++) {
      int row = q * 4 + rr;
      int n = nb + nn * 16 + r;
      Cc[(size_t)(m0 + row) * F + n] = (_Float16)accs[nn][rr];
    }
  }
}

// ---------- layer-2 aggregation + bias + relu + per-block max ----------
__global__ __launch_bounds__(256) void agg2_k(const _Float16* __restrict__ xw2,
                                              const int* __restrict__ offs,
                                              const int* __restrict__ csr,
                                              const float* __restrict__ dinv,
                                              const float* __restrict__ b2,
                                              float* __restrict__ partial, int N) {
  __shared__ int s_src[CH];
  __shared__ float s_w[CH];
  int f = threadIdx.x;
  float lmax = 0.f;
  for (int node = blockIdx.x; node < N; node += gridDim.x) {
    int beg = offs[node], end = offs[node + 1];
    float di = dinv[node];
    float acc = 0.f;
    for (int c = beg; c < end; c += CH) {
      int m = min(CH, end - c);
      __syncthreads();
      if (f < m) { int s = csr[c + f]; s_src[f] = s; s_w[f] = dinv[s]; }
      __syncthreads();
      #pragma unroll 4
      for (int e = 0; e < m; e++) acc += s_w[e] * (float)xw2[s_src[e] * F + f];
    }
    float v = di * acc + di * di * (float)xw2[node * F + f] + b2[f];
    lmax = fmaxf(lmax, fmaxf(v, 0.f));
  }
  partial[(size_t)blockIdx.x * F + f] = lmax;
}

__global__ __launch_bounds__(256) void maxred_k(const float* __restrict__ partial,
                                                float* __restrict__ out, int nrows) {
  int f = threadIdx.x;
  float lm = 0.f;
  for (int r = blockIdx.x; r < nrows; r += gridDim.x)
    lm = fmaxf(lm, partial[(size_t)r * F + f]);
  // relu outputs are >= 0, so int-punned max is order-correct; out pre-zeroed
  atomicMax((int*)&out[f], __float_as_int(lm));
}

extern "C" void kernel_launch(void* const* d_in, const int* in_sizes, int n_in,
                              void* d_out, int out_size, void* d_ws, size_t ws_size,
                              hipStream_t stream) {
  const float* x  = (const float*)d_in[0];
  const int*   ei = (const int*)d_in[1];
  const float* W1 = (const float*)d_in[2];
  const float* b1 = (const float*)d_in[3];
  const float* W2 = (const float*)d_in[4];
  const float* b2 = (const float*)d_in[5];
  const int E = in_sizes[1] / 2;
  const int N = NNODES;
  const int* src = ei;
  const int* dst = ei + E;

  char* w = (char*)d_ws;
  size_t off = 0;
  auto take = [&](size_t bytes) -> void* {
    void* p = w + off;
    off += (bytes + 255) & ~(size_t)255;
    return p;
  };
  int*       cnt    = (int*)take((size_t)N * 4);
  int*       offs   = (int*)take((size_t)(N + 1) * 4);
  int*       cursor = (int*)take((size_t)N * 4);
  float*     dinv   = (float*)take((size_t)N * 4);
  int*       csr    = (int*)take((size_t)E * 4);
  _Float16*  W1t    = (_Float16*)take((size_t)H * F * 2);
  _Float16*  W2t    = (_Float16*)take((size_t)F * H * 2);
  _Float16*  axh    = (_Float16*)take((size_t)N * F * 2);
  _Float16*  h1h    = (_Float16*)take((size_t)N * H * 2);
  _Float16*  xw2h   = (_Float16*)take((size_t)N * F * 2);
  const int AGG_GRID = 2048;
  float*     partial = (float*)take((size_t)AGG_GRID * F * 4);

  hipMemsetAsync(cnt, 0, (size_t)N * 4, stream);
  hipMemsetAsync(cursor, 0, (size_t)N * 4, stream);
  hipMemsetAsync(d_out, 0, (size_t)out_size * 4, stream);

  count_k<<<(E + 255) / 256, 256, 0, stream>>>(dst, cnt, E);
  scan_k<<<1, 1024, 0, stream>>>(cnt, offs, dinv, N);
  fill_k<<<(E + 255) / 256, 256, 0, stream>>>(src, dst, offs, cursor, csr, E);
  convw_k<<<(F * H + 255) / 256, 256, 0, stream>>>(W1, W1t, F, H);
  convw_k<<<(F * H + 255) / 256, 256, 0, stream>>>(W2, W2t, H, F);
  agg1_k<<<AGG_GRID, 256, 0, stream>>>(x, offs, csr, dinv, axh, N);
  gemm1_k<<<dim3(N / 16, 2), 256, 0, stream>>>(axh, W1t, b1, h1h);
  gemm2_k<<<N / 16, 256, 0, stream>>>(h1h, W2t, xw2h);
  agg2_k<<<AGG_GRID, 256, 0, stream>>>(xw2h, offs, csr, dinv, b2, partial, N);
  maxred_k<<<32, 256, 0, stream>>>(partial, (float*)d_out, AGG_GRID);
}